// Round 2
// baseline (435.549 us; speedup 1.0000x reference)
//
#include <hip/hip_runtime.h>

#define N 8192
#define DIM 128
#define NCHUNK 64            // j-chunks in pass 1 -> partial[NCHUNK][N]
#define JTILE (N / NCHUNK)   // 128 j per pass-1 block

typedef float f32x4 __attribute__((ext_vector_type(4)));

// ---------------------------------------------------------------------------
// Pass 0: encoder MLP. 128 -> 64 -> 32 -> 16 -> 16, relu on first three.
// v2: TWO threads per row (t&31 = row, t>>5 = output-half). 256 blocks x 64
// threads = 16384 threads -> every CU active (was 128 blocks / half the CUs
// idle), and per-thread FMA count halves (5504 vs 11008). Cross-half
// activation exchange goes through LDS; block = exactly one wave, so LDS
// program order makes write-before-read safe (same property the verified v1
// relied on for its sW1/sh2 aliasing).
// ---------------------------------------------------------------------------
__global__ __launch_bounds__(64) void encoder_kernel(
    const float* __restrict__ x,
    const float* __restrict__ W1, const float* __restrict__ b1,
    const float* __restrict__ W2, const float* __restrict__ b2,
    const float* __restrict__ W3, const float* __restrict__ b3,
    const float* __restrict__ W4, const float* __restrict__ b4,
    float* __restrict__ z, float* __restrict__ sqout)
{
    __shared__ float sW1[128 * 64];
    __shared__ float sW2[64 * 32];
    __shared__ float sW3[32 * 16];
    __shared__ float sW4[16 * 16];
    __shared__ float sb1[64];
    __shared__ float sb2[32];
    __shared__ float sb3[16];
    __shared__ float sb4[16];
    __shared__ float sh1[32 * 65];   // 32 rows, stride 65: bank (r+k)%32, <=2-way (free)
    __shared__ float sh2[32 * 33];
    __shared__ float sh3[32 * 17];

    int t = threadIdx.x;
    int r = t & 31;    // local row
    int h = t >> 5;    // output half (0/1)

    for (int idx = t; idx < 128 * 64; idx += 64) sW1[idx] = W1[idx];
    for (int idx = t; idx < 64 * 32; idx += 64) sW2[idx] = W2[idx];
    for (int idx = t; idx < 32 * 16; idx += 64) sW3[idx] = W3[idx];
    for (int idx = t; idx < 16 * 16; idx += 64) sW4[idx] = W4[idx];
    sb1[t] = b1[t];
    if (t < 32) sb2[t] = b2[t];
    if (t < 16) { sb3[t] = b3[t]; sb4[t] = b4[t]; }
    __syncthreads();

    int row = blockIdx.x * 32 + r;
    const float4* xr = (const float4*)(x + (size_t)row * DIM);

    // ---- layer 1: 128 -> 64, this thread computes outputs [h*32, h*32+32) ----
    float h1[32];
    #pragma unroll
    for (int k = 0; k < 32; ++k) h1[k] = sb1[h * 32 + k];
    for (int j4 = 0; j4 < 32; ++j4) {
        float4 xv = xr[j4];
        const float* w0 = &sW1[(j4 * 4 + 0) * 64 + h * 32];
        const float* w1 = &sW1[(j4 * 4 + 1) * 64 + h * 32];
        const float* w2 = &sW1[(j4 * 4 + 2) * 64 + h * 32];
        const float* w3 = &sW1[(j4 * 4 + 3) * 64 + h * 32];
        #pragma unroll
        for (int k = 0; k < 32; ++k) h1[k] = fmaf(xv.x, w0[k], h1[k]);
        #pragma unroll
        for (int k = 0; k < 32; ++k) h1[k] = fmaf(xv.y, w1[k], h1[k]);
        #pragma unroll
        for (int k = 0; k < 32; ++k) h1[k] = fmaf(xv.z, w2[k], h1[k]);
        #pragma unroll
        for (int k = 0; k < 32; ++k) h1[k] = fmaf(xv.w, w3[k], h1[k]);
    }
    #pragma unroll
    for (int k = 0; k < 32; ++k) sh1[r * 65 + h * 32 + k] = fmaxf(h1[k], 0.0f);

    // ---- layer 2: 64 -> 32, outputs [h*16, h*16+16), inputs all 64 ----
    // (single-wave block: layer-1 LDS writes precede these reads in program order)
    float h2[16];
    #pragma unroll
    for (int k = 0; k < 16; ++k) h2[k] = sb2[h * 16 + k];
    for (int j = 0; j < 64; ++j) {
        float a = sh1[r * 65 + j];
        #pragma unroll
        for (int k = 0; k < 16; ++k) h2[k] = fmaf(a, sW2[j * 32 + h * 16 + k], h2[k]);
    }
    #pragma unroll
    for (int k = 0; k < 16; ++k) sh2[r * 33 + h * 16 + k] = fmaxf(h2[k], 0.0f);

    // ---- layer 3: 32 -> 16, outputs [h*8, h*8+8) ----
    float h3[8];
    #pragma unroll
    for (int k = 0; k < 8; ++k) h3[k] = sb3[h * 8 + k];
    for (int j = 0; j < 32; ++j) {
        float a = sh2[r * 33 + j];
        #pragma unroll
        for (int k = 0; k < 8; ++k) h3[k] = fmaf(a, sW3[j * 16 + h * 8 + k], h3[k]);
    }
    #pragma unroll
    for (int k = 0; k < 8; ++k) sh3[r * 17 + h * 8 + k] = fmaxf(h3[k], 0.0f);

    // ---- layer 4: 16 -> 16, no relu, outputs [h*8, h*8+8) ----
    float zo[8];
    #pragma unroll
    for (int k = 0; k < 8; ++k) zo[k] = sb4[h * 8 + k];
    for (int j = 0; j < 16; ++j) {
        float a = sh3[r * 17 + j];
        #pragma unroll
        for (int k = 0; k < 8; ++k) zo[k] = fmaf(a, sW4[j * 16 + h * 8 + k], zo[k]);
    }

    float s = 0.0f;
    #pragma unroll
    for (int k = 0; k < 8; ++k) s = fmaf(zo[k], zo[k], s);
    s += __shfl_xor(s, 32, 64);          // combine the two halves' partial sums
    if (h == 0) sqout[row] = s;
    float4* zr = (float4*)(z + (size_t)row * 16 + h * 8);
    zr[0] = make_float4(zo[0], zo[1], zo[2], zo[3]);
    zr[1] = make_float4(zo[4], zo[5], zo[6], zo[7]);
}

// ---------------------------------------------------------------------------
// Pass 1: row sums of numerator = 1/(1+dist). Grid (8 rowblocks, 64 jchunks).
// v2: each thread owns FOUR rows (i0 + {0,1,2,3}*2048) with zi in registers
// -> 64 dots per broadcast ds_read_b128 (was 32), halving DS-pipe pressure.
// One 128-wide j tile per block staged in LDS (broadcast reads).
// ---------------------------------------------------------------------------
__global__ __launch_bounds__(256) void pass1_kernel(
    const float* __restrict__ z, const float* __restrict__ sq,
    float* __restrict__ partial)
{
    __shared__ float s_zj[JTILE * 16];
    __shared__ float s_sqj[JTILE];

    int t = threadIdx.x;
    int i0 = blockIdx.x * 256 + t;       // 0..2047
    int jb = blockIdx.y * JTILE;

    if (t < JTILE) {
        const float4* src = (const float4*)(z + (size_t)(jb + t) * 16);
        float4* dst = (float4*)(s_zj + t * 16);
        dst[0] = src[0]; dst[1] = src[1]; dst[2] = src[2]; dst[3] = src[3];
        s_sqj[t] = sq[jb + t];
    }

    float zi[4][16];
    float sqi[4];
    #pragma unroll
    for (int rr = 0; rr < 4; ++rr) {
        const float4* p = (const float4*)(z + (size_t)(i0 + rr * 2048) * 16);
        #pragma unroll
        for (int q = 0; q < 4; ++q) {
            float4 v = p[q];
            zi[rr][4*q]   = v.x; zi[rr][4*q+1] = v.y;
            zi[rr][4*q+2] = v.z; zi[rr][4*q+3] = v.w;
        }
        sqi[rr] = sq[i0 + rr * 2048];
    }
    __syncthreads();

    float acc0 = 0.0f, acc1 = 0.0f, acc2 = 0.0f, acc3 = 0.0f;
    #pragma unroll 2
    for (int jj = 0; jj < JTILE; ++jj) {
        const float* zj = s_zj + jj * 16;
        float d0 = 0.0f, d1 = 0.0f, d2 = 0.0f, d3 = 0.0f;
        #pragma unroll
        for (int k = 0; k < 16; ++k) {
            float w = zj[k];
            d0 = fmaf(zi[0][k], w, d0);
            d1 = fmaf(zi[1][k], w, d1);
            d2 = fmaf(zi[2][k], w, d2);
            d3 = fmaf(zi[3][k], w, d3);
        }
        float sj = s_sqj[jj];
        float t0 = fmaxf(fmaf(-2.0f, d0, sqi[0] + sj), 0.0f);
        float t1 = fmaxf(fmaf(-2.0f, d1, sqi[1] + sj), 0.0f);
        float t2 = fmaxf(fmaf(-2.0f, d2, sqi[2] + sj), 0.0f);
        float t3 = fmaxf(fmaf(-2.0f, d3, sqi[3] + sj), 0.0f);
        acc0 += __builtin_amdgcn_rcpf(1.0f + t0);
        acc1 += __builtin_amdgcn_rcpf(1.0f + t1);
        acc2 += __builtin_amdgcn_rcpf(1.0f + t2);
        acc3 += __builtin_amdgcn_rcpf(1.0f + t3);
    }
    size_t pb = (size_t)blockIdx.y * N + i0;
    partial[pb]            = acc0;
    partial[pb + 1 * 2048] = acc1;
    partial[pb + 2 * 2048] = acc2;
    partial[pb + 3 * 2048] = acc3;
}

// ---------------------------------------------------------------------------
// Pass 2: recompute numerators, scale by 1/rowsum, stream to out.
// v2: block owns 4 i-rows; zi held in REGISTERS for the whole sweep (block-
// uniform loads -> scalarizable), so the steady-state loop issues ZERO LDS
// ops (v1 re-read s_zi every tile: ~4M broadcast ds_read_b128 device-wide).
// Each thread owns 4 consecutive j -> float4 nontemporal stores (1 KB/wave
// inst). Grid 2048 blocks (4x v1) for latency hiding.
// ---------------------------------------------------------------------------
__global__ __launch_bounds__(256) void pass2_kernel(
    const float* __restrict__ z, const float* __restrict__ sq,
    const float* __restrict__ partial, float* __restrict__ out)
{
    __shared__ float s_inv[4];

    int t = threadIdx.x;
    int ibase = blockIdx.x * 4;
    int w = t >> 6, lane = t & 63;

    // rowsum: wave w reduces the NCHUNK=64 partials of row ibase+w
    {
        float v = partial[(size_t)lane * N + ibase + w];
        #pragma unroll
        for (int off = 32; off > 0; off >>= 1) v += __shfl_xor(v, off, 64);
        if (lane == 0) s_inv[w] = 1.0f / v;
    }

    float zi[4][16];
    float sqi[4];
    #pragma unroll
    for (int rr = 0; rr < 4; ++rr) {
        const float4* p = (const float4*)(z + (size_t)(ibase + rr) * 16);
        #pragma unroll
        for (int q = 0; q < 4; ++q) {
            float4 v = p[q];
            zi[rr][4*q]   = v.x; zi[rr][4*q+1] = v.y;
            zi[rr][4*q+2] = v.z; zi[rr][4*q+3] = v.w;
        }
        sqi[rr] = sq[ibase + rr];
    }
    __syncthreads();
    float inv[4];
    #pragma unroll
    for (int rr = 0; rr < 4; ++rr) inv[rr] = s_inv[rr];

    for (int jb = 0; jb < N; jb += 1024) {
        int j0 = jb + t * 4;
        float zj[4][16];
        #pragma unroll
        for (int q = 0; q < 4; ++q) {
            const float4* p = (const float4*)(z + (size_t)(j0 + q) * 16);
            #pragma unroll
            for (int qq = 0; qq < 4; ++qq) {
                float4 v = p[qq];
                zj[q][4*qq]   = v.x; zj[q][4*qq+1] = v.y;
                zj[q][4*qq+2] = v.z; zj[q][4*qq+3] = v.w;
            }
        }
        float4 sqjv = *(const float4*)(sq + j0);
        float sqj[4] = {sqjv.x, sqjv.y, sqjv.z, sqjv.w};

        #pragma unroll
        for (int rr = 0; rr < 4; ++rr) {
            float dd[4];
            #pragma unroll
            for (int q = 0; q < 4; ++q) {
                float d = 0.0f;
                #pragma unroll
                for (int k = 0; k < 16; ++k) d = fmaf(zi[rr][k], zj[q][k], d);
                float dist = fmaxf(fmaf(-2.0f, d, sqi[rr] + sqj[q]), 0.0f);
                dd[q] = __builtin_amdgcn_rcpf(1.0f + dist) * inv[rr];
            }
            f32x4 rv = {dd[0], dd[1], dd[2], dd[3]};
            __builtin_nontemporal_store(rv,
                (f32x4*)(out + (size_t)(ibase + rr) * N + j0));
        }
    }
}

extern "C" void kernel_launch(void* const* d_in, const int* in_sizes, int n_in,
                              void* d_out, int out_size, void* d_ws, size_t ws_size,
                              hipStream_t stream) {
    const float* x  = (const float*)d_in[0];
    const float* W1 = (const float*)d_in[1];
    const float* b1 = (const float*)d_in[2];
    const float* W2 = (const float*)d_in[3];
    const float* b2 = (const float*)d_in[4];
    const float* W3 = (const float*)d_in[5];
    const float* b3 = (const float*)d_in[6];
    const float* W4 = (const float*)d_in[7];
    const float* b4 = (const float*)d_in[8];
    float* out = (float*)d_out;

    float* ws = (float*)d_ws;
    float* z       = ws;                    // N*16        = 131072 floats
    float* sqv     = ws + N * 16;           // N           =   8192 floats
    float* partial = ws + N * 16 + N;       // NCHUNK*N    = 524288 floats
    // total ws usage: 663552 floats = 2.53 MiB

    encoder_kernel<<<256, 64, 0, stream>>>(x, W1, b1, W2, b2, W3, b3, W4, b4, z, sqv);
    pass1_kernel<<<dim3(8, NCHUNK), 256, 0, stream>>>(z, sqv, partial);
    pass2_kernel<<<N / 4, 256, 0, stream>>>(z, sqv, partial, out);
}

// Round 3
// 376.884 us; speedup vs baseline: 1.1557x; 1.1557x over previous
//
#include <hip/hip_runtime.h>

#define N 8192
#define DIM 128
#define NCHUNK 32   // j-chunks in pass 1 -> partial[NCHUNK][N]

typedef float f32x4 __attribute__((ext_vector_type(4)));

// ---------------------------------------------------------------------------
// Pass 0: encoder MLP. 128 -> 64 -> 32 -> 16 -> 16, relu on first three.
// v1 structure verbatim (measured-good at 395 us total): one thread per row,
// 64-thread blocks (1 wave), weights staged in LDS, hidden activations
// round-trip through padded per-thread LDS columns. ONLY change: also emit a
// transposed copy z_T[16][N] (16 coalesced scalar stores) for pass 2's
// j-streaming loads.
// ---------------------------------------------------------------------------
__global__ __launch_bounds__(64) void encoder_kernel(
    const float* __restrict__ x,
    const float* __restrict__ W1, const float* __restrict__ b1,
    const float* __restrict__ W2, const float* __restrict__ b2,
    const float* __restrict__ W3, const float* __restrict__ b3,
    const float* __restrict__ W4, const float* __restrict__ b4,
    float* __restrict__ z, float* __restrict__ zT, float* __restrict__ sqout)
{
    __shared__ float sW2[64 * 32];
    __shared__ float sW3[32 * 16];
    __shared__ float sW4[16 * 16];
    __shared__ float sb1[64];
    __shared__ float sb2[32];
    __shared__ float sb3[16];
    __shared__ float sb4[16];
    __shared__ float sW1[128 * 64];   // reused for h2/h3 staging after layer 1
    __shared__ float sh1[64 * 65];    // stride 65: bank = (t + k) % 32, conflict-free

    int t = threadIdx.x;
    float* sh2 = sW1;                 // 64*33 = 2112 floats
    float* sh3 = sW1 + 2112;          // 64*17 = 1088 floats  (3200 <= 8192, fits)

    for (int idx = t; idx < 128 * 64; idx += 64) sW1[idx] = W1[idx];
    for (int idx = t; idx < 64 * 32; idx += 64) sW2[idx] = W2[idx];
    for (int idx = t; idx < 32 * 16; idx += 64) sW3[idx] = W3[idx];
    for (int idx = t; idx < 16 * 16; idx += 64) sW4[idx] = W4[idx];
    sb1[t] = b1[t];
    if (t < 32) sb2[t] = b2[t];
    if (t < 16) { sb3[t] = b3[t]; sb4[t] = b4[t]; }
    __syncthreads();

    int row = blockIdx.x * 64 + t;
    const float4* xr = (const float4*)(x + (size_t)row * DIM);

    // ---- layer 1: 128 -> 64 ----
    float h1[64];
    #pragma unroll
    for (int k = 0; k < 64; ++k) h1[k] = sb1[k];
    for (int j4 = 0; j4 < 32; ++j4) {
        float4 xv = xr[j4];
        const float* w0 = &sW1[(j4 * 4 + 0) * 64];
        const float* w1 = &sW1[(j4 * 4 + 1) * 64];
        const float* w2 = &sW1[(j4 * 4 + 2) * 64];
        const float* w3 = &sW1[(j4 * 4 + 3) * 64];
        #pragma unroll
        for (int k = 0; k < 64; ++k) h1[k] = fmaf(xv.x, w0[k], h1[k]);
        #pragma unroll
        for (int k = 0; k < 64; ++k) h1[k] = fmaf(xv.y, w1[k], h1[k]);
        #pragma unroll
        for (int k = 0; k < 64; ++k) h1[k] = fmaf(xv.z, w2[k], h1[k]);
        #pragma unroll
        for (int k = 0; k < 64; ++k) h1[k] = fmaf(xv.w, w3[k], h1[k]);
    }
    #pragma unroll
    for (int k = 0; k < 64; ++k) sh1[t * 65 + k] = fmaxf(h1[k], 0.0f);

    // ---- layer 2: 64 -> 32 ----  (single-wave block: in-order LDS ops make
    // the sW1 -> sh2 reuse safe; layer-1 reads complete before these writes)
    float h2[32];
    #pragma unroll
    for (int k = 0; k < 32; ++k) h2[k] = sb2[k];
    for (int j = 0; j < 64; ++j) {
        float a = sh1[t * 65 + j];
        #pragma unroll
        for (int k = 0; k < 32; ++k) h2[k] = fmaf(a, sW2[j * 32 + k], h2[k]);
    }
    #pragma unroll
    for (int k = 0; k < 32; ++k) sh2[t * 33 + k] = fmaxf(h2[k], 0.0f);

    // ---- layer 3: 32 -> 16 ----
    float h3[16];
    #pragma unroll
    for (int k = 0; k < 16; ++k) h3[k] = sb3[k];
    for (int j = 0; j < 32; ++j) {
        float a = sh2[t * 33 + j];
        #pragma unroll
        for (int k = 0; k < 16; ++k) h3[k] = fmaf(a, sW3[j * 16 + k], h3[k]);
    }
    #pragma unroll
    for (int k = 0; k < 16; ++k) sh3[t * 17 + k] = fmaxf(h3[k], 0.0f);

    // ---- layer 4: 16 -> 16, no relu ----
    float zo[16];
    #pragma unroll
    for (int k = 0; k < 16; ++k) zo[k] = sb4[k];
    for (int j = 0; j < 16; ++j) {
        float a = sh3[t * 17 + j];
        #pragma unroll
        for (int k = 0; k < 16; ++k) zo[k] = fmaf(a, sW4[j * 16 + k], zo[k]);
    }

    float s = 0.0f;
    #pragma unroll
    for (int k = 0; k < 16; ++k) s = fmaf(zo[k], zo[k], s);
    sqout[row] = s;
    float4* zr = (float4*)(z + (size_t)row * 16);
    zr[0] = make_float4(zo[0], zo[1], zo[2], zo[3]);
    zr[1] = make_float4(zo[4], zo[5], zo[6], zo[7]);
    zr[2] = make_float4(zo[8], zo[9], zo[10], zo[11]);
    zr[3] = make_float4(zo[12], zo[13], zo[14], zo[15]);
    // transposed copy: lane stride 4 B per k -> 16 perfectly coalesced stores
    #pragma unroll
    for (int k = 0; k < 16; ++k) zT[(size_t)k * N + row] = zo[k];
}

// ---------------------------------------------------------------------------
// Pass 1: row sums of numerator = 1/(1+dist). Grid (16 rowblocks, 32 jchunks).
// v1 verbatim (measured-good): each thread owns rows i0 and i0+4096, one
// 256-wide j tile per block staged in LDS (all-lane broadcast reads).
// ---------------------------------------------------------------------------
__global__ __launch_bounds__(256) void pass1_kernel(
    const float* __restrict__ z, const float* __restrict__ sq,
    float* __restrict__ partial)
{
    __shared__ float s_zj[256 * 16];
    __shared__ float s_sqj[256];

    int t = threadIdx.x;
    int i0 = blockIdx.x * 256 + t;      // 0..4095
    int i1 = i0 + 4096;
    int jb = blockIdx.y * 256;

    // stage z tile for this block's j range
    {
        const float4* src = (const float4*)(z + (size_t)(jb + t) * 16);
        float4* dst = (float4*)(s_zj + t * 16);
        dst[0] = src[0]; dst[1] = src[1]; dst[2] = src[2]; dst[3] = src[3];
        s_sqj[t] = sq[jb + t];
    }

    float zi0[16], zi1[16];
    {
        const float4* p0 = (const float4*)(z + (size_t)i0 * 16);
        const float4* p1 = (const float4*)(z + (size_t)i1 * 16);
        #pragma unroll
        for (int q = 0; q < 4; ++q) {
            float4 v0 = p0[q]; float4 v1 = p1[q];
            zi0[4*q] = v0.x; zi0[4*q+1] = v0.y; zi0[4*q+2] = v0.z; zi0[4*q+3] = v0.w;
            zi1[4*q] = v1.x; zi1[4*q+1] = v1.y; zi1[4*q+2] = v1.z; zi1[4*q+3] = v1.w;
        }
    }
    float sqi0 = sq[i0], sqi1 = sq[i1];
    __syncthreads();

    float acc0 = 0.0f, acc1 = 0.0f;
    #pragma unroll 4
    for (int jj = 0; jj < 256; ++jj) {
        const float* zj = s_zj + jj * 16;
        float d0 = 0.0f, d1 = 0.0f;
        #pragma unroll
        for (int k = 0; k < 16; ++k) {
            float w = zj[k];
            d0 = fmaf(zi0[k], w, d0);
            d1 = fmaf(zi1[k], w, d1);
        }
        float sj = s_sqj[jj];
        float dist0 = fmaxf(fmaf(-2.0f, d0, sqi0 + sj), 0.0f);
        float dist1 = fmaxf(fmaf(-2.0f, d1, sqi1 + sj), 0.0f);
        acc0 += __builtin_amdgcn_rcpf(1.0f + dist0);
        acc1 += __builtin_amdgcn_rcpf(1.0f + dist1);
    }
    partial[blockIdx.y * N + i0] = acc0;
    partial[blockIdx.y * N + i1] = acc1;
}

// ---------------------------------------------------------------------------
// Pass 2: recompute numerators, scale by 1/rowsum, stream to out.
// v3 (the ONLY changed kernel this round): block owns 4 i-rows held entirely
// in registers/SGPRs -> ZERO LDS ops in the steady-state sweep (v1 issued
// 64 broadcast ds_read_b128 per thread per 256-j tile: ~80 us of DS-pipe
// occupancy device-wide by the m134 12-cyc/b128 model). zj streams from the
// TRANSPOSED z_T so every load instruction is a contiguous 1-KB wave access
// (the round-1 version's 256-B lane stride touched 64 lines/instr). Each
// thread owns 4 consecutive j -> f32x4 nontemporal stores. 2048 blocks.
// ---------------------------------------------------------------------------
__global__ __launch_bounds__(256) void pass2_kernel(
    const float* __restrict__ z, const float* __restrict__ zT,
    const float* __restrict__ sq,
    const float* __restrict__ partial, float* __restrict__ out)
{
    __shared__ float s_inv[4];

    int t = threadIdx.x;
    int ibase = blockIdx.x * 4;
    int w = t >> 6, lane = t & 63;

    // rowsum: wave w reduces the NCHUNK=32 partials of row ibase+w
    {
        float v = (lane < NCHUNK) ? partial[(size_t)lane * N + ibase + w] : 0.0f;
        #pragma unroll
        for (int off = 32; off > 0; off >>= 1) v += __shfl_xor(v, off, 64);
        if (lane == 0) s_inv[w] = 1.0f / v;
    }

    float zi[4][16];
    float sqi[4];
    #pragma unroll
    for (int rr = 0; rr < 4; ++rr) {
        const float4* p = (const float4*)(z + (size_t)(ibase + rr) * 16);
        #pragma unroll
        for (int q = 0; q < 4; ++q) {
            float4 v = p[q];
            zi[rr][4*q]   = v.x; zi[rr][4*q+1] = v.y;
            zi[rr][4*q+2] = v.z; zi[rr][4*q+3] = v.w;
        }
        sqi[rr] = sq[ibase + rr];
    }
    __syncthreads();
    float inv[4];
    #pragma unroll
    for (int rr = 0; rr < 4; ++rr) inv[rr] = s_inv[rr];

    for (int jb = 0; jb < N; jb += 1024) {
        int j0 = jb + t * 4;
        // 16 contiguous 1-KB wave loads: zjT[k] = z^T[k][j0..j0+3]
        f32x4 zjT[16];
        #pragma unroll
        for (int k = 0; k < 16; ++k)
            zjT[k] = *(const f32x4*)(zT + (size_t)k * N + j0);
        f32x4 sqj = *(const f32x4*)(sq + j0);

        #pragma unroll
        for (int rr = 0; rr < 4; ++rr) {
            f32x4 d = {0.0f, 0.0f, 0.0f, 0.0f};
            #pragma unroll
            for (int k = 0; k < 16; ++k) d += zi[rr][k] * zjT[k];
            f32x4 dist = sqi[rr] + sqj - 2.0f * d;
            f32x4 num;
            num.x = __builtin_amdgcn_rcpf(1.0f + fmaxf(dist.x, 0.0f)) * inv[rr];
            num.y = __builtin_amdgcn_rcpf(1.0f + fmaxf(dist.y, 0.0f)) * inv[rr];
            num.z = __builtin_amdgcn_rcpf(1.0f + fmaxf(dist.z, 0.0f)) * inv[rr];
            num.w = __builtin_amdgcn_rcpf(1.0f + fmaxf(dist.w, 0.0f)) * inv[rr];
            __builtin_nontemporal_store(num,
                (f32x4*)(out + (size_t)(ibase + rr) * N + j0));
        }
    }
}

extern "C" void kernel_launch(void* const* d_in, const int* in_sizes, int n_in,
                              void* d_out, int out_size, void* d_ws, size_t ws_size,
                              hipStream_t stream) {
    const float* x  = (const float*)d_in[0];
    const float* W1 = (const float*)d_in[1];
    const float* b1 = (const float*)d_in[2];
    const float* W2 = (const float*)d_in[3];
    const float* b2 = (const float*)d_in[4];
    const float* W3 = (const float*)d_in[5];
    const float* b3 = (const float*)d_in[6];
    const float* W4 = (const float*)d_in[7];
    const float* b4 = (const float*)d_in[8];
    float* out = (float*)d_out;

    float* ws = (float*)d_ws;
    float* z       = ws;                        // N*16     = 131072 floats
    float* zT      = ws + N * 16;               // 16*N     = 131072 floats
    float* sqv     = ws + N * 32;               // N        =   8192 floats
    float* partial = ws + N * 32 + N;           // NCHUNK*N = 262144 floats
    // total ws usage: 532480 floats = 2.03 MiB

    encoder_kernel<<<128, 64, 0, stream>>>(x, W1, b1, W2, b2, W3, b3, W4, b4, z, zT, sqv);
    pass1_kernel<<<dim3(16, NCHUNK), 256, 0, stream>>>(z, sqv, partial);
    pass2_kernel<<<N / 4, 256, 0, stream>>>(z, zT, sqv, partial, out);
}